// Round 1
// baseline (430.474 us; speedup 1.0000x reference)
//
#include <hip/hip_runtime.h>

// Input:  x[b][c][h][w], B=8, C=32, H=512, W=512 (fp32)
// Output: out[b][q][c][h2][w2], q in {LL,LH,HL,HH}, h2=H/2, w2=W/2 (fp32)
//
// Each thread: loads float4 from row 2*h2 and row 2*h2+1 (4 input cols),
// produces 2 output cols for each of the 4 quadrants (float2 stores).

#define B_   8
#define C_   32
#define H2_  256
#define W2_  256
#define WPAIRS_ (W2_/2)          // 128 float4-covered output pairs per row

__global__ __launch_bounds__(256)
void WaveletTransform_14319420965150_kernel(const float* __restrict__ x,
                                            float* __restrict__ out) {
    int tid = blockIdx.x * blockDim.x + threadIdx.x;
    // decompose: tid = ((b*32 + c)*256 + h2)*128 + wp
    int wp = tid & (WPAIRS_ - 1);        // 0..127
    int h2 = (tid >> 7) & (H2_ - 1);     // 0..255
    int c  = (tid >> 15) & (C_ - 1);     // 0..31
    int b  = tid >> 20;                  // 0..7

    // input rows 2*h2 and 2*h2+1 of image (b,c); row stride 512 floats
    const float4* row0 = (const float4*)(x + ((((size_t)b * C_ + c) * 512 + 2 * h2) * 512));
    const float4* row1 = row0 + (512 / 4);
    float4 t = row0[wp];   // x00a x01a x00b x01b
    float4 u = row1[wp];   // x10a x11a x10b x11b

    float2 LL, LH, HL, HH;
    {
        float s0 = t.x + t.y, d0 = t.x - t.y;   // top sum/diff (pixel a)
        float s1 = u.x + u.y, d1 = u.x - u.y;   // bot sum/diff (pixel a)
        LL.x = (s0 + s1) * 0.5f;
        LH.x = (s0 - s1) * 0.5f;
        HL.x = (d0 + d1) * 0.5f;
        HH.x = (d0 - d1) * 0.5f;
    }
    {
        float s0 = t.z + t.w, d0 = t.z - t.w;   // pixel b
        float s1 = u.z + u.w, d1 = u.z - u.w;
        LL.y = (s0 + s1) * 0.5f;
        LH.y = (s0 - s1) * 0.5f;
        HL.y = (d0 + d1) * 0.5f;
        HH.y = (d0 - d1) * 0.5f;
    }

    // output float2 index: ((b*4 + q)*C + c)*H2*W2/2 + h2*W2/2 + wp
    float2* o = (float2*)out;
    size_t obase = (((size_t)b * 4) * C_ + c) * (H2_ * W2_ / 2)
                 + (size_t)h2 * (W2_ / 2) + wp;
    const size_t qstride = (size_t)C_ * (H2_ * W2_ / 2);  // one quadrant block
    o[obase]               = LL;
    o[obase +     qstride] = LH;
    o[obase + 2 * qstride] = HL;
    o[obase + 3 * qstride] = HH;
}

extern "C" void kernel_launch(void* const* d_in, const int* in_sizes, int n_in,
                              void* d_out, int out_size, void* d_ws, size_t ws_size,
                              hipStream_t stream) {
    const float* x = (const float*)d_in[0];
    float* out = (float*)d_out;
    // total threads = B*C*H2*WPAIRS = 8*32*256*128 = 8,388,608
    const int total = B_ * C_ * H2_ * WPAIRS_;
    const int block = 256;
    const int grid = total / block;  // 32768
    WaveletTransform_14319420965150_kernel<<<grid, block, 0, stream>>>(x, out);
}